// Round 1
// baseline (25789.484 us; speedup 1.0000x reference)
//
#include <hip/hip_runtime.h>

// Problem constants (match reference)
#define BB   64
#define TT   256   // TE == TD == 256
#define EE   256
#define HH   512
#define VV   128
#define N4H  2048  // 4*H
#define NT128 128  // n-tiles for N=2048

typedef unsigned short u16;
typedef _Float16 half8 __attribute__((ext_vector_type(8)));
typedef float    f32x4 __attribute__((ext_vector_type(4)));

static __device__ __forceinline__ half8 as_half8(uint4 v) {
    return __builtin_bit_cast(half8, v);
}

static __device__ __forceinline__ float sigmf(float x) {
    return 1.0f / (1.0f + expf(-x));
}

// ---------------------------------------------------------------------------
// Weight split + tile kernel.
// Splits fp32 weights into f16 hi + f16 lo(*2048) and lays them out
// fragment-major for mfma_f32_16x16x32_f16 B-operands:
//   out[((kt*NT + nt)*64 + lane)*8 + i]  where lane = 16*((k&31)>>3) + (n&15),
//   k = kt*32 + 8*(lane>>4) + i,  n = nt*16 + (lane&15).
// Row remap: srcrow = (k < thresh) ? k : k + rowoff  (handles decW0 slicing).
// ---------------------------------------------------------------------------
__global__ void split_tile(const float* __restrict__ W,
                           u16* __restrict__ dh, u16* __restrict__ dl,
                           int NTt, int thresh, int rowoff, int nsrc, int total)
{
    int o = blockIdx.x * 256 + threadIdx.x;
    if (o >= total) return;
    int i    = o & 7;
    int lane = (o >> 3) & 63;
    int tile = o >> 9;
    int nt   = tile % NTt;
    int kt   = tile / NTt;
    int k = kt * 32 + ((lane >> 4) << 3) + i;
    int n = nt * 16 + (lane & 15);
    int srcrow = (k < thresh) ? k : (k + rowoff);
    float a = W[(size_t)srcrow * nsrc + n];
    _Float16 ah = (_Float16)a;
    float r = a - (float)ah;
    _Float16 al = (_Float16)(r * 2048.0f);  // scaled lo: avoids f16 denormals
    dh[o] = __builtin_bit_cast(u16, ah);
    dl[o] = __builtin_bit_cast(u16, al);
}

// ---------------------------------------------------------------------------
// One LSTM layer step (or the prefix GEMM) for all 64 batch rows.
// Grid: 32 WGs x 256 thr (4 waves). WG g owns h-dims [g*16, g*16+16),
// i.e. gate n-tiles {g, g+32, g+64, g+96}. Wave w owns batch rows [16w,16w+16).
// z = x @ W + init computed via f16 hi/lo split (3 MFMAs per K-chunk per gate),
// gates + masking + state ping-pong fused in the epilogue.
// ---------------------------------------------------------------------------
enum StepMode { M_L0 = 0, M_L1 = 1, M_PREFIX = 2 };

template<int MODE, bool WRITE_OUT>
__global__ __launch_bounds__(256) void step_kernel(
    const u16*   __restrict__ Bh,     // tiled weight hi
    const u16*   __restrict__ Bl,     // tiled weight lo (*2048)
    const float* __restrict__ emb,    // embedding table  (L0)
    const int*   __restrict__ toks,   // token ids [B][T] (L0)
    const float* __restrict__ seg0,   // L0: h_own_prev; L1: h_low(t); PREFIX: h1
    const float* __restrict__ seg1,   // L1: h_own_prev
    const float* __restrict__ bias,   // z init (broadcast over rows)
    const float* __restrict__ prefix, // DEC_L0: per-row z init [B][4H]
    const float* __restrict__ c_in,
    float*       __restrict__ c_out,
    float*       __restrict__ h_out,
    u16*         __restrict__ dout,   // dec_out f16 [B][T][H] (WRITE_OUT)
    float*       __restrict__ prefout,// PREFIX output [B][4H]
    const int*   __restrict__ lens,
    int t, int K)
{
    __shared__ uint4 ldsv[512];   // 8 KB: 4 gates x {hi,lo} x 64 lanes x 16B

    const int tid  = threadIdx.x;
    const int lane = tid & 63;
    const int wave = tid >> 6;
    const int g    = blockIdx.x;          // 0..31 h-dim group
    const int m0   = wave * 16;           // batch row base
    const int arow = m0 + (lane & 15);    // A-fragment row (batch)
    const int kgrp = lane >> 4;           // 0..3
    const int d    = g * 16 + (lane & 15);// owned h-dim (C/D col = lane&15)

    int tok = 0;
    if (MODE == M_L0) tok = toks[arow * TT + t];

    // accumulators: acc_hi + acc_lo*2^-11
    f32x4 acch[4], accl[4];
#pragma unroll
    for (int q = 0; q < 4; ++q) {
        if (MODE == M_L0 && prefix) {
#pragma unroll
            for (int r = 0; r < 4; ++r)
                acch[q][r] = prefix[(size_t)(m0 + (lane >> 4) * 4 + r) * N4H + q * HH + d];
        } else {
            float bv = bias[q * HH + d];
            f32x4 tmp = {bv, bv, bv, bv};
            acch[q] = tmp;
        }
        f32x4 z = {0.f, 0.f, 0.f, 0.f};
        accl[q] = z;
    }

    const int KT = K >> 5;
    for (int kt = 0; kt < KT; ++kt) {
        __syncthreads();
        // stage this K-chunk's B fragments: 512 x 16B
#pragma unroll
        for (int e2 = 0; e2 < 2; ++e2) {
            int e  = tid + e2 * 256;
            int q  = e >> 7;
            int hl = (e >> 6) & 1;
            int ln = e & 63;
            size_t idx = (((size_t)kt * NT128 + (g + q * 32)) * 64 + ln) * 8;
            const u16* s = (hl ? Bl : Bh) + idx;
            ldsv[e] = *(const uint4*)s;
        }
        __syncthreads();

        // A fragment: 8 consecutive k of fp32 x, split to f16 hi/lo
        int ka = kt * 32 + kgrp * 8;
        const float* asrc;
        if (MODE == M_L0)
            asrc = (ka < EE) ? (emb + (size_t)tok * EE + ka)
                             : (seg0 + (size_t)arow * HH + (ka - EE));
        else if (MODE == M_L1)
            asrc = (ka < HH) ? (seg0 + (size_t)arow * HH + ka)
                             : (seg1 + (size_t)arow * HH + (ka - HH));
        else
            asrc = seg0 + (size_t)arow * HH + ka;

        float4 xa = *(const float4*)asrc;
        float4 xb = *(const float4*)(asrc + 4);
        float xs[8] = {xa.x, xa.y, xa.z, xa.w, xb.x, xb.y, xb.z, xb.w};
        half8 ah, al;
#pragma unroll
        for (int i = 0; i < 8; ++i) {
            _Float16 hi = (_Float16)xs[i];
            ah[i] = hi;
            al[i] = (_Float16)((xs[i] - (float)hi) * 2048.0f);
        }

#pragma unroll
        for (int q = 0; q < 4; ++q) {
            half8 bh = as_half8(ldsv[q * 128 + lane]);
            half8 bl = as_half8(ldsv[q * 128 + 64 + lane]);
            acch[q] = __builtin_amdgcn_mfma_f32_16x16x32_f16(ah, bh, acch[q], 0, 0, 0);
            accl[q] = __builtin_amdgcn_mfma_f32_16x16x32_f16(ah, bl, accl[q], 0, 0, 0);
            accl[q] = __builtin_amdgcn_mfma_f32_16x16x32_f16(al, bh, accl[q], 0, 0, 0);
        }
    }

    const float inv2048 = 1.0f / 2048.0f;

    if (MODE == M_PREFIX) {
#pragma unroll
        for (int q = 0; q < 4; ++q)
#pragma unroll
            for (int r = 0; r < 4; ++r) {
                int b = m0 + (lane >> 4) * 4 + r;
                prefout[(size_t)b * N4H + q * HH + d] = acch[q][r] + accl[q][r] * inv2048;
            }
        return;
    }

    // gates epilogue; C/D layout: col = lane&15 (=d), row = (lane>>4)*4 + r
    const float* h_in = (MODE == M_L0) ? seg0 : seg1;
#pragma unroll
    for (int r = 0; r < 4; ++r) {
        int b = m0 + (lane >> 4) * 4 + r;
        float zi = acch[0][r] + accl[0][r] * inv2048;
        float zj = acch[1][r] + accl[1][r] * inv2048;
        float zf = acch[2][r] + accl[2][r] * inv2048;
        float zo = acch[3][r] + accl[3][r] * inv2048;
        float c = c_in[b * HH + d];
        float h = h_in[b * HH + d];
        float fs = sigmf(zf + 1.0f);   // forget_bias = 1.0
        float is = sigmf(zi);
        float jt = tanhf(zj);
        float os = sigmf(zo);
        float nc = c * fs + is * jt;
        float nh = tanhf(nc) * os;
        bool msk = (t < lens[b]);
        if (!msk) { nc = c; nh = h; }  // freeze state past length
        c_out[b * HH + d] = nc;
        h_out[b * HH + d] = nh;
        if (WRITE_OUT) {
            _Float16 ov = (_Float16)(msk ? nh : 0.0f);  // output zeroed past length
            dout[((size_t)b * TT + t) * HH + d] = __builtin_bit_cast(u16, ov);
        }
    }
}

// ---------------------------------------------------------------------------
// Final projection: [B*TD, H] (f16) @ projW (f16) + projb -> d_out fp32.
// Grid: 256 WGs x 4 waves; wave handles one 16-row m-tile x all 8 n-tiles.
// Single-f16 precision suffices here (error ~3e-5 << 1e-3 threshold).
// ---------------------------------------------------------------------------
__global__ __launch_bounds__(256) void proj_kernel(
    const u16* __restrict__ Bh, const u16* __restrict__ A,
    const float* __restrict__ bias, float* __restrict__ out)
{
    const int tid  = threadIdx.x;
    const int lane = tid & 63;
    const int wave = tid >> 6;
    const int mt   = blockIdx.x * 4 + wave;  // 0..1023
    const int rowbase = mt * 16;
    const int arow = rowbase + (lane & 15);
    const int kgrp = lane >> 4;

    f32x4 acc[8];
#pragma unroll
    for (int nt = 0; nt < 8; ++nt) {
        float bv = bias[nt * 16 + (lane & 15)];
        f32x4 tmp = {bv, bv, bv, bv};
        acc[nt] = tmp;
    }
    for (int kt = 0; kt < 16; ++kt) {
        int ka = kt * 32 + kgrp * 8;
        half8 ah = as_half8(*(const uint4*)(A + (size_t)arow * HH + ka));
#pragma unroll
        for (int nt = 0; nt < 8; ++nt) {
            half8 bh = as_half8(*(const uint4*)(Bh + (((size_t)kt * 8 + nt) * 64 + lane) * 8));
            acc[nt] = __builtin_amdgcn_mfma_f32_16x16x32_f16(ah, bh, acc[nt], 0, 0, 0);
        }
    }
#pragma unroll
    for (int nt = 0; nt < 8; ++nt)
#pragma unroll
        for (int r = 0; r < 4; ++r)
            out[(size_t)(rowbase + kgrp * 4 + r) * VV + nt * 16 + (lane & 15)] =
                acc[nt][r];
}

// ---------------------------------------------------------------------------
extern "C" void kernel_launch(void* const* d_in, const int* in_sizes, int n_in,
                              void* d_out, int out_size, void* d_ws, size_t ws_size,
                              hipStream_t stream)
{
    const int*   en_in  = (const int*)  d_in[0];
    const int*   en_len = (const int*)  d_in[1];
    const int*   de_in  = (const int*)  d_in[2];
    const int*   de_len = (const int*)  d_in[3];
    const float* embed  = (const float*)d_in[4];
    const float* encW0  = (const float*)d_in[5];
    const float* encb0  = (const float*)d_in[6];
    const float* encW1  = (const float*)d_in[7];
    const float* encb1  = (const float*)d_in[8];
    const float* decW0  = (const float*)d_in[9];
    const float* decb0  = (const float*)d_in[10];
    const float* decW1  = (const float*)d_in[11];
    const float* decb1  = (const float*)d_in[12];
    const float* projW  = (const float*)d_in[13];
    const float* projb  = (const float*)d_in[14];

    char* base = (char*)d_ws;
    size_t off = 0;
    auto alloc = [&](size_t bytes) -> void* {
        void* r = base + off;
        off = (off + bytes + 255) & ~(size_t)255;
        return r;
    };

    // state ping-pong buffers (step t reads parity t&1, writes (t+1)&1)
    float* states = (float*)alloc(8 * (size_t)BB * HH * sizeof(float));
    float* c0[2] = {states + 0 * BB * HH, states + 1 * BB * HH};
    float* h0[2] = {states + 2 * BB * HH, states + 3 * BB * HH};
    float* c1[2] = {states + 4 * BB * HH, states + 5 * BB * HH};
    float* h1[2] = {states + 6 * BB * HH, states + 7 * BB * HH};
    float* prefix  = (float*)alloc((size_t)BB * N4H * sizeof(float));
    u16*   dec_out = (u16*)  alloc((size_t)BB * TT * HH * sizeof(u16));

    auto aw = [&](size_t elems) -> u16* { return (u16*)alloc(elems * sizeof(u16)); };
    const size_t sz768 = (size_t)768 * N4H, sz1024 = (size_t)1024 * N4H;
    const size_t sz512 = (size_t)512 * N4H, szproj = (size_t)512 * VV;
    u16 *e0h = aw(sz768),  *e0l = aw(sz768);
    u16 *e1h = aw(sz1024), *e1l = aw(sz1024);
    u16 *d0h = aw(sz768),  *d0l = aw(sz768);   // decW0 rows {0..255, 768..1279}
    u16 *dmh = aw(sz512),  *dml = aw(sz512);   // decW0 rows {256..767} (en_last)
    u16 *d1h = aw(sz1024), *d1l = aw(sz1024);
    u16 *prh = aw(szproj), *prl = aw(szproj);

    auto launch_split = [&](const float* W, u16* dh, u16* dl, int K, int NTt,
                            int thresh, int rowoff, int nsrc) {
        int total = K * NTt * 16;
        split_tile<<<(total + 255) / 256, 256, 0, stream>>>(W, dh, dl, NTt, thresh,
                                                            rowoff, nsrc, total);
    };
    launch_split(encW0, e0h, e0l, 768,  NT128, 768,  0,   N4H);
    launch_split(encW1, e1h, e1l, 1024, NT128, 1024, 0,   N4H);
    launch_split(decW0, d0h, d0l, 768,  NT128, 256,  512, N4H);
    launch_split(decW0, dmh, dml, 512,  NT128, 0,    256, N4H);
    launch_split(decW1, d1h, d1l, 1024, NT128, 1024, 0,   N4H);
    launch_split(projW, prh, prl, 512,  8,     512,  0,   VV);

    hipMemsetAsync(states, 0, 8 * (size_t)BB * HH * sizeof(float), stream);

    // ---------------- encoder ----------------
    for (int t = 0; t < TT; ++t) {
        int p = t & 1, q = (t + 1) & 1;
        step_kernel<M_L0, false><<<32, 256, 0, stream>>>(
            e0h, e0l, embed, en_in, h0[p], nullptr, encb0, nullptr,
            c0[p], c0[q], h0[q], nullptr, nullptr, en_len, t, 768);
        step_kernel<M_L1, false><<<32, 256, 0, stream>>>(
            e1h, e1l, nullptr, nullptr, h0[q], h1[p], encb1, nullptr,
            c1[p], c1[q], h1[q], nullptr, nullptr, en_len, t, 1024);
    }

    // en_last = final h1 (state frozen past length) -> decoder L0 prefix
    step_kernel<M_PREFIX, false><<<32, 256, 0, stream>>>(
        dmh, dml, nullptr, nullptr, h1[0], nullptr, decb0, nullptr,
        nullptr, nullptr, nullptr, nullptr, prefix, de_len, 0, 512);

    // ---------------- decoder (init state = encoder final state) ----------------
    for (int t = 0; t < TT; ++t) {
        int p = t & 1, q = (t + 1) & 1;
        step_kernel<M_L0, false><<<32, 256, 0, stream>>>(
            d0h, d0l, embed, de_in, h0[p], nullptr, nullptr, prefix,
            c0[p], c0[q], h0[q], nullptr, nullptr, de_len, t, 768);
        step_kernel<M_L1, true><<<32, 256, 0, stream>>>(
            d1h, d1l, nullptr, nullptr, h0[q], h1[p], decb1, nullptr,
            c1[p], c1[q], h1[q], dec_out, nullptr, de_len, t, 1024);
    }

    // ---------------- projection ----------------
    proj_kernel<<<256, 256, 0, stream>>>(prh, dec_out, projb, (float*)d_out);
}

// Round 2
// 19537.794 us; speedup vs baseline: 1.3200x; 1.3200x over previous
//
#include <hip/hip_runtime.h>

#define BB   64
#define TT   256
#define EE   256
#define HH   512
#define VV   128
#define NBLK 256
#define BH   (BB*HH)   // 32768 per h buffer

typedef unsigned short u16;
typedef _Float16 half8 __attribute__((ext_vector_type(8)));
typedef float    f32x4 __attribute__((ext_vector_type(4)));

static __device__ __forceinline__ half8 as_half8(uint4 v) { return __builtin_bit_cast(half8, v); }
static __device__ __forceinline__ u16  h_bits(_Float16 h) { return __builtin_bit_cast(u16, h); }

// ---------------------------------------------------------------------------
// Gate-packed weight tiling for the persistent kernel's LDS slices.
// Layout: [wg(128)][kt(KT)][hl(2)][lane(64)][i(8)] u16.
// n-tile col c = lane&15 -> gate q = c>>2, hd = c&3, col n = q*512 + wg*4 + hd.
// k = kt*32 + (lane>>4)*8 + i ; srcrow = (k<thresh) ? k : k+rowoff.
// ---------------------------------------------------------------------------
__global__ void split_pack(const float* __restrict__ W, u16* __restrict__ dst,
                           int KT, int thresh, int rowoff, int total)
{
    int o = blockIdx.x * 256 + threadIdx.x;
    if (o >= total) return;
    int i    = o & 7;
    int lane = (o >> 3) & 63;
    int hl   = (o >> 9) & 1;
    int rest = o >> 10;
    int kt   = rest % KT;
    int wg   = rest / KT;
    int c  = lane & 15;
    int n  = (c >> 2) * 512 + wg * 4 + (c & 3);
    int k  = kt * 32 + ((lane >> 4) << 3) + i;
    int srcrow = (k < thresh) ? k : (k + rowoff);
    float a = W[(size_t)srcrow * 2048 + n];
    _Float16 ah = (_Float16)a;
    dst[o] = hl ? h_bits((_Float16)((a - (float)ah) * 2048.0f)) : h_bits(ah);
}

// old layout for the projection weights: [kt][nt][lane][i], hi only used
__global__ void split_tile(const float* __restrict__ W,
                           u16* __restrict__ dh, u16* __restrict__ dl,
                           int NTt, int nsrc, int total)
{
    int o = blockIdx.x * 256 + threadIdx.x;
    if (o >= total) return;
    int i    = o & 7;
    int lane = (o >> 3) & 63;
    int tile = o >> 9;
    int nt   = tile % NTt;
    int kt   = tile / NTt;
    int k = kt * 32 + ((lane >> 4) << 3) + i;
    int n = nt * 16 + (lane & 15);
    float a = W[(size_t)k * nsrc + n];
    _Float16 ah = (_Float16)a;
    dh[o] = h_bits(ah);
    dl[o] = h_bits((_Float16)((a - (float)ah) * 2048.0f));
}

__global__ void split_embed(const float* __restrict__ E,
                            u16* __restrict__ hi, u16* __restrict__ lo, int total)
{
    int o = blockIdx.x * 256 + threadIdx.x;
    if (o >= total) return;
    float a = E[o];
    _Float16 ah = (_Float16)a;
    hi[o] = h_bits(ah);
    lo[o] = h_bits((_Float16)((a - (float)ah) * 2048.0f));
}

// ---------------------------------------------------------------------------
// K-loop: 3-MFMA f16 hi/lo split per chunk; B from LDS, A from global (f16).
// Pointers are pre-offset by (row*stride + kgrp*8); ldsl = lds + lane.
// ---------------------------------------------------------------------------
template<int KT, int SPLIT>
__device__ __forceinline__ void dostep(const uint4* __restrict__ ldsl,
    const u16* __restrict__ s0h, const u16* __restrict__ s0l,
    const u16* __restrict__ s1h, const u16* __restrict__ s1l,
    f32x4& acch, f32x4& accl)
{
#pragma unroll
    for (int kt = 0; kt < KT; ++kt) {
        const int off = kt * 32;
        const u16* ph = (off < SPLIT) ? s0h + off : s1h + (off - SPLIT);
        const u16* pl = (off < SPLIT) ? s0l + off : s1l + (off - SPLIT);
        half8 ah = as_half8(*(const uint4*)ph);
        half8 al = as_half8(*(const uint4*)pl);
        half8 bh = as_half8(ldsl[(kt * 2 + 0) * 64]);
        half8 bl = as_half8(ldsl[(kt * 2 + 1) * 64]);
        acch = __builtin_amdgcn_mfma_f32_16x16x32_f16(ah, bh, acch, 0, 0, 0);
        accl = __builtin_amdgcn_mfma_f32_16x16x32_f16(ah, bl, accl, 0, 0, 0);
        accl = __builtin_amdgcn_mfma_f32_16x16x32_f16(al, bh, accl, 0, 0, 0);
    }
}

// grid barrier: agent-scope counter + fences (all 256 blocks resident)
static __device__ __forceinline__ void gbar(int* cnt, int target)
{
    __syncthreads();
    if (threadIdx.x == 0) {
        __threadfence();
        __hip_atomic_fetch_add(cnt, 1, __ATOMIC_ACQ_REL, __HIP_MEMORY_SCOPE_AGENT);
        while (__hip_atomic_load(cnt, __ATOMIC_ACQUIRE, __HIP_MEMORY_SCOPE_AGENT) < target)
            __builtin_amdgcn_s_sleep(1);
        __threadfence();
    }
    __syncthreads();
}

// ---------------------------------------------------------------------------
// Persistent kernel: encoder (257 iters) -> prefix+LDS reload -> decoder (257)
// -> projection. Blocks 0..127 = layer0, 128..255 = layer1. WG g owns h-dims
// [4g,4g+4). Wave w owns batch rows [16w,16w+16). c,h state in registers.
// ---------------------------------------------------------------------------
__global__ __launch_bounds__(256) void persist(
    const u16* __restrict__ e0t, const u16* __restrict__ e1t,
    const u16* __restrict__ d0t, const u16* __restrict__ d1t,
    const u16* __restrict__ dmt, const u16* __restrict__ prt,
    const u16* __restrict__ embh, const u16* __restrict__ embl,
    const int* __restrict__ en_in, const int* __restrict__ en_len,
    const int* __restrict__ de_in, const int* __restrict__ de_len,
    const float* __restrict__ encb0, const float* __restrict__ encb1,
    const float* __restrict__ decb0, const float* __restrict__ decb1,
    const float* __restrict__ projb,
    u16* __restrict__ hbuf, u16* __restrict__ dec_out,
    int* __restrict__ barcnt, float* __restrict__ dout)
{
    __shared__ uint4 lds[4096];   // 64 KB

    const int tid  = threadIdx.x;
    const int lane = tid & 63;
    const int wave = tid >> 6;
    const int bid  = blockIdx.x;
    const int layer = bid >> 7;
    const int g     = bid & 127;
    const int c    = lane & 15;
    const int q    = c >> 2;
    const int hd   = c & 3;
    const int kgrp = lane >> 4;
    const int d    = g * 4 + hd;
    const int arow  = wave * 16 + c;        // A-fragment batch row
    const int bbase = wave * 16 + kgrp * 4; // C rows base
    const float inv2048 = 1.0f / 2048.0f;
    const uint4* ldsl = lds + lane;
    int ep = 0;

    auto HB = [&](int which, int p) -> u16* {  // 0=h0hi 1=h0lo 2=h1hi 3=h1lo
        return hbuf + (size_t)(which * 2 + p) * BH;
    };

    int lenE[4], lenD[4];
#pragma unroll
    for (int r = 0; r < 4; ++r) { lenE[r] = en_len[bbase + r]; lenD[r] = de_len[bbase + r]; }

    float cst[4]  = {0.f, 0.f, 0.f, 0.f};
    float hreg[4] = {0.f, 0.f, 0.f, 0.f};

    const float bE = (layer ? encb1 : encb0)[q * HH + d];
    const float bD1 = decb1[q * HH + d];

    // epilogue: gather 4 gates across lanes, LSTM cell, masked state update
    auto epi = [&](f32x4 acch, f32x4 accl, const int* lens, int t,
                   u16* whh, u16* whl, u16* dot) {
        float zi[4], zj[4], zf[4], zo[4];
        int lb = lane & 0x33;
#pragma unroll
        for (int r = 0; r < 4; ++r) {
            float z = acch[r] + accl[r] * inv2048;
            zi[r] = __shfl(z, lb,      64);
            zj[r] = __shfl(z, lb | 4,  64);
            zf[r] = __shfl(z, lb | 8,  64);
            zo[r] = __shfl(z, lb | 12, 64);
        }
#pragma unroll
        for (int r = 0; r < 4; ++r) {
            int b = bbase + r;
            float fs = 1.f / (1.f + expf(-(zf[r] + 1.f)));
            float is = 1.f / (1.f + expf(-zi[r]));
            float jt = tanhf(zj[r]);
            float os = 1.f / (1.f + expf(-zo[r]));
            float nc = cst[r] * fs + is * jt;
            float nh = tanhf(nc) * os;
            bool mk = (t < lens[r]);
            nc = mk ? nc : cst[r];
            nh = mk ? nh : hreg[r];
            cst[r] = nc; hreg[r] = nh;
            if (q == 0) {
                _Float16 hh = (_Float16)nh;
                _Float16 hl = (_Float16)((nh - (float)hh) * 2048.0f);
                whh[b * HH + d] = h_bits(hh);
                whl[b * HH + d] = h_bits(hl);
                if (dot) {
                    _Float16 ov = (_Float16)(mk ? nh : 0.0f);
                    dot[((size_t)b * TT + t) * HH + d] = h_bits(ov);
                }
            }
        }
    };

    // ---- stage encoder weights to LDS
    {
        const u16* src = layer ? e1t : e0t;
        int nv = (layer ? 32 : 24) * 128;
        const uint4* s4 = (const uint4*)src + (size_t)g * nv;
        for (int j = tid; j < nv; j += 256) lds[j] = s4[j];
    }
    __syncthreads();

    // =================== encoder ===================
    for (int k = 0; k <= 256; ++k) {
        if (layer == 0) {
            if (k < 256) {
                int t = k, p = k & 1, pp = p ^ 1;
                int tok = en_in[arow * TT + t];
                f32x4 acch = {bE, bE, bE, bE}, accl = {0.f, 0.f, 0.f, 0.f};
                dostep<24, 256>(ldsl,
                    embh + (size_t)tok * EE + kgrp * 8, embl + (size_t)tok * EE + kgrp * 8,
                    HB(0, pp) + (size_t)arow * HH + kgrp * 8, HB(1, pp) + (size_t)arow * HH + kgrp * 8,
                    acch, accl);
                epi(acch, accl, lenE, t, HB(0, p), HB(1, p), nullptr);
            }
        } else {
            if (k >= 1) {
                int t = k - 1, p = t & 1, pp = p ^ 1;
                f32x4 acch = {bE, bE, bE, bE}, accl = {0.f, 0.f, 0.f, 0.f};
                dostep<32, 512>(ldsl,
                    HB(0, p) + (size_t)arow * HH + kgrp * 8, HB(1, p) + (size_t)arow * HH + kgrp * 8,
                    HB(2, pp) + (size_t)arow * HH + kgrp * 8, HB(3, pp) + (size_t)arow * HH + kgrp * 8,
                    acch, accl);
                epi(acch, accl, lenE, t, HB(2, p), HB(3, p), nullptr);
            }
        }
        ep += NBLK; gbar(barcnt, ep);
    }

    // =================== prefix (dec L0 z-init from en_last) + LDS reload ===
    f32x4 prefreg = {0.f, 0.f, 0.f, 0.f};
    if (layer == 0) {
        float bv = decb0[q * HH + d];
        f32x4 ph = {bv, bv, bv, bv}, pl = {0.f, 0.f, 0.f, 0.f};
        const u16* s0h = HB(2, 1) + (size_t)arow * HH + kgrp * 8;
        const u16* s0l = HB(3, 1) + (size_t)arow * HH + kgrp * 8;
#pragma unroll
        for (int kt = 0; kt < 16; ++kt) {
            half8 ah = as_half8(*(const uint4*)(s0h + kt * 32));
            half8 al = as_half8(*(const uint4*)(s0l + kt * 32));
            const u16* bb = dmt + (size_t)(g * 16 + kt) * 1024;
            half8 bh = as_half8(*(const uint4*)(bb + lane * 8));
            half8 bl = as_half8(*(const uint4*)(bb + 512 + lane * 8));
            ph = __builtin_amdgcn_mfma_f32_16x16x32_f16(ah, bh, ph, 0, 0, 0);
            pl = __builtin_amdgcn_mfma_f32_16x16x32_f16(ah, bl, pl, 0, 0, 0);
            pl = __builtin_amdgcn_mfma_f32_16x16x32_f16(al, bh, pl, 0, 0, 0);
        }
#pragma unroll
        for (int r = 0; r < 4; ++r) prefreg[r] = ph[r] + pl[r] * inv2048;
    }
    __syncthreads();
    {
        const u16* src = layer ? d1t : d0t;
        int nv = (layer ? 32 : 24) * 128;
        const uint4* s4 = (const uint4*)src + (size_t)g * nv;
        for (int j = tid; j < nv; j += 256) lds[j] = s4[j];
    }
    __syncthreads();
    ep += NBLK; gbar(barcnt, ep);

    // =================== decoder ===================
    for (int k = 0; k <= 256; ++k) {
        if (layer == 0) {
            if (k < 256) {
                int t = k, p = k & 1, pp = p ^ 1;
                int tok = de_in[arow * TT + t];
                f32x4 acch = prefreg, accl = {0.f, 0.f, 0.f, 0.f};
                dostep<24, 256>(ldsl,
                    embh + (size_t)tok * EE + kgrp * 8, embl + (size_t)tok * EE + kgrp * 8,
                    HB(0, pp) + (size_t)arow * HH + kgrp * 8, HB(1, pp) + (size_t)arow * HH + kgrp * 8,
                    acch, accl);
                epi(acch, accl, lenD, t, HB(0, p), HB(1, p), nullptr);
            }
        } else {
            if (k >= 1) {
                int t = k - 1, p = t & 1, pp = p ^ 1;
                f32x4 acch = {bD1, bD1, bD1, bD1}, accl = {0.f, 0.f, 0.f, 0.f};
                dostep<32, 512>(ldsl,
                    HB(0, p) + (size_t)arow * HH + kgrp * 8, HB(1, p) + (size_t)arow * HH + kgrp * 8,
                    HB(2, pp) + (size_t)arow * HH + kgrp * 8, HB(3, pp) + (size_t)arow * HH + kgrp * 8,
                    acch, accl);
                epi(acch, accl, lenD, t, HB(2, p), HB(3, p), dec_out);
            }
        }
        ep += NBLK; gbar(barcnt, ep);
    }

    // =================== projection: [16384,512](f16) @ [512,128] + b ======
    {
        int rowb = bid * 64 + wave * 16;
        f32x4 acc[8];
#pragma unroll
        for (int nt = 0; nt < 8; ++nt) {
            float bv = projb[nt * 16 + c];
            f32x4 tmp = {bv, bv, bv, bv};
            acc[nt] = tmp;
        }
        const u16* ap = dec_out + (size_t)(rowb + c) * HH + kgrp * 8;
#pragma unroll
        for (int kt = 0; kt < 16; ++kt) {
            half8 ah = as_half8(*(const uint4*)(ap + kt * 32));
#pragma unroll
            for (int nt = 0; nt < 8; ++nt) {
                half8 bh = as_half8(*(const uint4*)(prt + ((size_t)(kt * 8 + nt) * 64 + lane) * 8));
                acc[nt] = __builtin_amdgcn_mfma_f32_16x16x32_f16(ah, bh, acc[nt], 0, 0, 0);
            }
        }
#pragma unroll
        for (int nt = 0; nt < 8; ++nt)
#pragma unroll
            for (int r = 0; r < 4; ++r)
                dout[(size_t)(rowb + kgrp * 4 + r) * VV + nt * 16 + c] = acc[nt][r];
    }
}

// ---------------------------------------------------------------------------
extern "C" void kernel_launch(void* const* d_in, const int* in_sizes, int n_in,
                              void* d_out, int out_size, void* d_ws, size_t ws_size,
                              hipStream_t stream)
{
    const int*   en_in  = (const int*)  d_in[0];
    const int*   en_len = (const int*)  d_in[1];
    const int*   de_in  = (const int*)  d_in[2];
    const int*   de_len = (const int*)  d_in[3];
    const float* embed  = (const float*)d_in[4];
    const float* encW0  = (const float*)d_in[5];
    const float* encb0  = (const float*)d_in[6];
    const float* encW1  = (const float*)d_in[7];
    const float* encb1  = (const float*)d_in[8];
    const float* decW0  = (const float*)d_in[9];
    const float* decb0  = (const float*)d_in[10];
    const float* decW1  = (const float*)d_in[11];
    const float* decb1  = (const float*)d_in[12];
    const float* projW  = (const float*)d_in[13];
    const float* projb  = (const float*)d_in[14];

    char* base = (char*)d_ws;
    size_t off = 0;
    auto alloc = [&](size_t bytes) -> void* {
        void* r = base + off;
        off = (off + bytes + 255) & ~(size_t)255;
        return r;
    };

    u16* hbuf    = (u16*)alloc((size_t)8 * BH * sizeof(u16));       // 512 KB
    u16* dec_out = (u16*)alloc((size_t)BB * TT * HH * sizeof(u16)); // 16 MB
    int* barcnt  = (int*)alloc(256);

    auto aw = [&](size_t elems) -> u16* { return (u16*)alloc(elems * sizeof(u16)); };
    const size_t szK768  = (size_t)128 * 24 * 1024;  // 3.1M u16
    const size_t szK1024 = (size_t)128 * 32 * 1024;
    const size_t szK512  = (size_t)128 * 16 * 1024;
    u16* e0t = aw(szK768);
    u16* e1t = aw(szK1024);
    u16* d0t = aw(szK768);
    u16* d1t = aw(szK1024);
    u16* dmt = aw(szK512);
    u16* prh = aw((size_t)512 * VV);
    u16* prl = aw((size_t)512 * VV);
    u16* embh = aw((size_t)VV * EE);
    u16* embl = aw((size_t)VV * EE);

    auto pack = [&](const float* W, u16* dst, int KT, int thresh, int rowoff) {
        int total = 128 * KT * 1024;
        split_pack<<<(total + 255) / 256, 256, 0, stream>>>(W, dst, KT, thresh, rowoff, total);
    };
    pack(encW0, e0t, 24, 768,  0);    // rows 0..767
    pack(encW1, e1t, 32, 1024, 0);
    pack(decW0, d0t, 24, 256,  512);  // rows {0..255, 768..1279}
    pack(decW0, dmt, 16, 0,    256);  // rows 256..767 (en_last block)
    pack(decW1, d1t, 32, 1024, 0);
    {
        int total = 512 * 8 * 16;
        split_tile<<<(total + 255) / 256, 256, 0, stream>>>(projW, prh, prl, 8, VV, total);
    }
    {
        int total = VV * EE;
        split_embed<<<(total + 255) / 256, 256, 0, stream>>>(embed, embh, embl, total);
    }

    hipMemsetAsync(hbuf, 0, (size_t)8 * BH * sizeof(u16), stream);
    hipMemsetAsync(barcnt, 0, 256, stream);

    persist<<<NBLK, 256, 0, stream>>>(
        e0t, e1t, d0t, d1t, dmt, prh, embh, embl,
        en_in, en_len, de_in, de_len,
        encb0, encb1, decb0, decb1, projb,
        hbuf, dec_out, barcnt, (float*)d_out);
}

// Round 3
// 8608.907 us; speedup vs baseline: 2.9957x; 2.2695x over previous
//
#include <hip/hip_runtime.h>

#define BB   64
#define TT   256
#define EE   256
#define HH   512
#define VV   128
#define NBLK 256
#define BH   (BB*HH)   // 32768 per h buffer

typedef unsigned short u16;
typedef _Float16 half8 __attribute__((ext_vector_type(8)));
typedef float    f32x4 __attribute__((ext_vector_type(4)));

static __device__ __forceinline__ half8 as_half8(uint4 v) { return __builtin_bit_cast(half8, v); }
static __device__ __forceinline__ u16  h_bits(_Float16 h) { return __builtin_bit_cast(u16, h); }

// ---------------------------------------------------------------------------
// Gate-packed weight tiling for the persistent kernel's LDS slices.
// Layout: [wg(128)][kt(KT)][hl(2)][lane(64)][i(8)] u16.
// n-tile col c = lane&15 -> gate q = c>>2, hd = c&3, col n = q*512 + wg*4 + hd.
// k = kt*32 + (lane>>4)*8 + i ; srcrow = (k<thresh) ? k : k+rowoff.
// ---------------------------------------------------------------------------
__global__ void split_pack(const float* __restrict__ W, u16* __restrict__ dst,
                           int KT, int thresh, int rowoff, int total)
{
    int o = blockIdx.x * 256 + threadIdx.x;
    if (o >= total) return;
    int i    = o & 7;
    int lane = (o >> 3) & 63;
    int hl   = (o >> 9) & 1;
    int rest = o >> 10;
    int kt   = rest % KT;
    int wg   = rest / KT;
    int c  = lane & 15;
    int n  = (c >> 2) * 512 + wg * 4 + (c & 3);
    int k  = kt * 32 + ((lane >> 4) << 3) + i;
    int srcrow = (k < thresh) ? k : (k + rowoff);
    float a = W[(size_t)srcrow * 2048 + n];
    _Float16 ah = (_Float16)a;
    dst[o] = hl ? h_bits((_Float16)((a - (float)ah) * 2048.0f)) : h_bits(ah);
}

// old layout for the projection weights: [kt][nt][lane][i], hi only used
__global__ void split_tile(const float* __restrict__ W,
                           u16* __restrict__ dh, u16* __restrict__ dl,
                           int NTt, int nsrc, int total)
{
    int o = blockIdx.x * 256 + threadIdx.x;
    if (o >= total) return;
    int i    = o & 7;
    int lane = (o >> 3) & 63;
    int tile = o >> 9;
    int nt   = tile % NTt;
    int kt   = tile / NTt;
    int k = kt * 32 + ((lane >> 4) << 3) + i;
    int n = nt * 16 + (lane & 15);
    float a = W[(size_t)k * nsrc + n];
    _Float16 ah = (_Float16)a;
    dh[o] = h_bits(ah);
    dl[o] = h_bits((_Float16)((a - (float)ah) * 2048.0f));
}

__global__ void split_embed(const float* __restrict__ E,
                            u16* __restrict__ hi, u16* __restrict__ lo, int total)
{
    int o = blockIdx.x * 256 + threadIdx.x;
    if (o >= total) return;
    float a = E[o];
    _Float16 ah = (_Float16)a;
    hi[o] = h_bits(ah);
    lo[o] = h_bits((_Float16)((a - (float)ah) * 2048.0f));
}

// ---------------------------------------------------------------------------
// K-loop: 3-MFMA f16 hi/lo split per chunk; B from LDS, A from global (f16).
// ---------------------------------------------------------------------------
template<int KT, int SPLIT>
__device__ __forceinline__ void dostep(const uint4* __restrict__ ldsl,
    const u16* __restrict__ s0h, const u16* __restrict__ s0l,
    const u16* __restrict__ s1h, const u16* __restrict__ s1l,
    f32x4& acch, f32x4& accl)
{
#pragma unroll
    for (int kt = 0; kt < KT; ++kt) {
        const int off = kt * 32;
        const u16* ph = (off < SPLIT) ? s0h + off : s1h + (off - SPLIT);
        const u16* pl = (off < SPLIT) ? s0l + off : s1l + (off - SPLIT);
        half8 ah = as_half8(*(const uint4*)ph);
        half8 al = as_half8(*(const uint4*)pl);
        half8 bh = as_half8(ldsl[(kt * 2 + 0) * 64]);
        half8 bl = as_half8(ldsl[(kt * 2 + 1) * 64]);
        acch = __builtin_amdgcn_mfma_f32_16x16x32_f16(ah, bh, acch, 0, 0, 0);
        accl = __builtin_amdgcn_mfma_f32_16x16x32_f16(ah, bl, accl, 0, 0, 0);
        accl = __builtin_amdgcn_mfma_f32_16x16x32_f16(al, bh, accl, 0, 0, 0);
    }
}

// ---------------------------------------------------------------------------
// Grid barrier, master-broadcast form (no contended RMW):
//  - block b release-stores epoch to its own cacheline arr[b*64]
//  - block 0: 256 threads poll one flag each (relaxed), acquire re-load,
//    then thread0 release-stores `go`
//  - other blocks: relaxed-poll `go`, acquire re-load, __syncthreads
// Ping-pong data buffers tolerate the <=1-step barrier-exit skew.
// ---------------------------------------------------------------------------
static __device__ __forceinline__ void gbar2(int* __restrict__ arr,
                                             int* __restrict__ go, int ep)
{
    __syncthreads();
    if (blockIdx.x == 0) {
        const int t = threadIdx.x;
        if (t > 0) {
            int* p = arr + t * 64;
            while (__hip_atomic_load(p, __ATOMIC_RELAXED, __HIP_MEMORY_SCOPE_AGENT) < ep) {}
            while (__hip_atomic_load(p, __ATOMIC_ACQUIRE, __HIP_MEMORY_SCOPE_AGENT) < ep) {}
        }
        __syncthreads();
        if (t == 0)
            __hip_atomic_store(go, ep, __ATOMIC_RELEASE, __HIP_MEMORY_SCOPE_AGENT);
    } else {
        if (threadIdx.x == 0) {
            __hip_atomic_store(arr + blockIdx.x * 64, ep, __ATOMIC_RELEASE,
                               __HIP_MEMORY_SCOPE_AGENT);
            while (__hip_atomic_load(go, __ATOMIC_RELAXED, __HIP_MEMORY_SCOPE_AGENT) < ep) {}
            while (__hip_atomic_load(go, __ATOMIC_ACQUIRE, __HIP_MEMORY_SCOPE_AGENT) < ep) {}
        }
        __syncthreads();
    }
}

// ---------------------------------------------------------------------------
// Persistent kernel: encoder (257 iters) -> prefix+LDS reload -> decoder (257)
// -> projection. Blocks 0..127 = layer0, 128..255 = layer1. WG g owns h-dims
// [4g,4g+4). Wave w owns batch rows [16w,16w+16). c,h state in registers.
// ---------------------------------------------------------------------------
__global__ __launch_bounds__(256) void persist(
    const u16* __restrict__ e0t, const u16* __restrict__ e1t,
    const u16* __restrict__ d0t, const u16* __restrict__ d1t,
    const u16* __restrict__ dmt, const u16* __restrict__ prt,
    const u16* __restrict__ embh, const u16* __restrict__ embl,
    const int* __restrict__ en_in, const int* __restrict__ en_len,
    const int* __restrict__ de_in, const int* __restrict__ de_len,
    const float* __restrict__ encb0, const float* __restrict__ encb1,
    const float* __restrict__ decb0, const float* __restrict__ decb1,
    const float* __restrict__ projb,
    u16* __restrict__ hbuf, u16* __restrict__ dec_out,
    int* __restrict__ arr, int* __restrict__ go, float* __restrict__ dout)
{
    __shared__ uint4 lds[4096];   // 64 KB

    const int tid  = threadIdx.x;
    const int lane = tid & 63;
    const int wave = tid >> 6;
    const int bid  = blockIdx.x;
    const int layer = bid >> 7;
    const int g     = bid & 127;
    const int c    = lane & 15;
    const int q    = c >> 2;
    const int hd   = c & 3;
    const int kgrp = lane >> 4;
    const int d    = g * 4 + hd;
    const int arow  = wave * 16 + c;        // A-fragment batch row
    const int bbase = wave * 16 + kgrp * 4; // C rows base
    const float inv2048 = 1.0f / 2048.0f;
    const uint4* ldsl = lds + lane;
    int ep = 0;

    auto HB = [&](int which, int p) -> u16* {  // 0=h0hi 1=h0lo 2=h1hi 3=h1lo
        return hbuf + (size_t)(which * 2 + p) * BH;
    };

    int lenE[4], lenD[4];
#pragma unroll
    for (int r = 0; r < 4; ++r) { lenE[r] = en_len[bbase + r]; lenD[r] = de_len[bbase + r]; }

    float cst[4]  = {0.f, 0.f, 0.f, 0.f};
    float hreg[4] = {0.f, 0.f, 0.f, 0.f};

    const float bE = (layer ? encb1 : encb0)[q * HH + d];
    const float bD1 = decb1[q * HH + d];

    // epilogue: gather 4 gates across lanes, LSTM cell, masked state update
    auto epi = [&](f32x4 acch, f32x4 accl, const int* lens, int t,
                   u16* whh, u16* whl, u16* dot) {
        float zi[4], zj[4], zf[4], zo[4];
        int lb = lane & 0x33;
#pragma unroll
        for (int r = 0; r < 4; ++r) {
            float z = acch[r] + accl[r] * inv2048;
            zi[r] = __shfl(z, lb,      64);
            zj[r] = __shfl(z, lb | 4,  64);
            zf[r] = __shfl(z, lb | 8,  64);
            zo[r] = __shfl(z, lb | 12, 64);
        }
#pragma unroll
        for (int r = 0; r < 4; ++r) {
            int b = bbase + r;
            float fs = 1.f / (1.f + expf(-(zf[r] + 1.f)));
            float is = 1.f / (1.f + expf(-zi[r]));
            float jt = tanhf(zj[r]);
            float os = 1.f / (1.f + expf(-zo[r]));
            float nc = cst[r] * fs + is * jt;
            float nh = tanhf(nc) * os;
            bool mk = (t < lens[r]);
            nc = mk ? nc : cst[r];
            nh = mk ? nh : hreg[r];
            cst[r] = nc; hreg[r] = nh;
            if (q == 0) {
                _Float16 hh = (_Float16)nh;
                _Float16 hl = (_Float16)((nh - (float)hh) * 2048.0f);
                whh[b * HH + d] = h_bits(hh);
                whl[b * HH + d] = h_bits(hl);
                if (dot) {
                    _Float16 ov = (_Float16)(mk ? nh : 0.0f);
                    dot[((size_t)b * TT + t) * HH + d] = h_bits(ov);
                }
            }
        }
    };

    // ---- stage encoder weights to LDS
    {
        const u16* src = layer ? e1t : e0t;
        int nv = (layer ? 32 : 24) * 128;
        const uint4* s4 = (const uint4*)src + (size_t)g * nv;
        for (int j = tid; j < nv; j += 256) lds[j] = s4[j];
    }
    __syncthreads();

    // =================== encoder ===================
    for (int k = 0; k <= 256; ++k) {
        if (layer == 0) {
            if (k < 256) {
                int t = k, p = k & 1, pp = p ^ 1;
                int tok = en_in[arow * TT + t];
                f32x4 acch = {bE, bE, bE, bE}, accl = {0.f, 0.f, 0.f, 0.f};
                dostep<24, 256>(ldsl,
                    embh + (size_t)tok * EE + kgrp * 8, embl + (size_t)tok * EE + kgrp * 8,
                    HB(0, pp) + (size_t)arow * HH + kgrp * 8, HB(1, pp) + (size_t)arow * HH + kgrp * 8,
                    acch, accl);
                epi(acch, accl, lenE, t, HB(0, p), HB(1, p), nullptr);
            }
        } else {
            if (k >= 1) {
                int t = k - 1, p = t & 1, pp = p ^ 1;
                f32x4 acch = {bE, bE, bE, bE}, accl = {0.f, 0.f, 0.f, 0.f};
                dostep<32, 512>(ldsl,
                    HB(0, p) + (size_t)arow * HH + kgrp * 8, HB(1, p) + (size_t)arow * HH + kgrp * 8,
                    HB(2, pp) + (size_t)arow * HH + kgrp * 8, HB(3, pp) + (size_t)arow * HH + kgrp * 8,
                    acch, accl);
                epi(acch, accl, lenE, t, HB(2, p), HB(3, p), nullptr);
            }
        }
        ++ep; gbar2(arr, go, ep);
    }

    // =================== prefix (dec L0 z-init from en_last) + LDS reload ===
    f32x4 prefreg = {0.f, 0.f, 0.f, 0.f};
    if (layer == 0) {
        float bv = decb0[q * HH + d];
        f32x4 ph = {bv, bv, bv, bv}, pl = {0.f, 0.f, 0.f, 0.f};
        const u16* s0h = HB(2, 1) + (size_t)arow * HH + kgrp * 8;
        const u16* s0l = HB(3, 1) + (size_t)arow * HH + kgrp * 8;
#pragma unroll
        for (int kt = 0; kt < 16; ++kt) {
            half8 ah = as_half8(*(const uint4*)(s0h + kt * 32));
            half8 al = as_half8(*(const uint4*)(s0l + kt * 32));
            const u16* bb = dmt + (size_t)(g * 16 + kt) * 1024;
            half8 bh = as_half8(*(const uint4*)(bb + lane * 8));
            half8 bl = as_half8(*(const uint4*)(bb + 512 + lane * 8));
            ph = __builtin_amdgcn_mfma_f32_16x16x32_f16(ah, bh, ph, 0, 0, 0);
            pl = __builtin_amdgcn_mfma_f32_16x16x32_f16(ah, bl, pl, 0, 0, 0);
            pl = __builtin_amdgcn_mfma_f32_16x16x32_f16(al, bh, pl, 0, 0, 0);
        }
#pragma unroll
        for (int r = 0; r < 4; ++r) prefreg[r] = ph[r] + pl[r] * inv2048;
    }
    __syncthreads();
    {
        const u16* src = layer ? d1t : d0t;
        int nv = (layer ? 32 : 24) * 128;
        const uint4* s4 = (const uint4*)src + (size_t)g * nv;
        for (int j = tid; j < nv; j += 256) lds[j] = s4[j];
    }
    __syncthreads();
    ++ep; gbar2(arr, go, ep);

    // =================== decoder ===================
    for (int k = 0; k <= 256; ++k) {
        if (layer == 0) {
            if (k < 256) {
                int t = k, p = k & 1, pp = p ^ 1;
                int tok = de_in[arow * TT + t];
                f32x4 acch = prefreg, accl = {0.f, 0.f, 0.f, 0.f};
                dostep<24, 256>(ldsl,
                    embh + (size_t)tok * EE + kgrp * 8, embl + (size_t)tok * EE + kgrp * 8,
                    HB(0, pp) + (size_t)arow * HH + kgrp * 8, HB(1, pp) + (size_t)arow * HH + kgrp * 8,
                    acch, accl);
                epi(acch, accl, lenD, t, HB(0, p), HB(1, p), nullptr);
            }
        } else {
            if (k >= 1) {
                int t = k - 1, p = t & 1, pp = p ^ 1;
                f32x4 acch = {bD1, bD1, bD1, bD1}, accl = {0.f, 0.f, 0.f, 0.f};
                dostep<32, 512>(ldsl,
                    HB(0, p) + (size_t)arow * HH + kgrp * 8, HB(1, p) + (size_t)arow * HH + kgrp * 8,
                    HB(2, pp) + (size_t)arow * HH + kgrp * 8, HB(3, pp) + (size_t)arow * HH + kgrp * 8,
                    acch, accl);
                epi(acch, accl, lenD, t, HB(2, p), HB(3, p), dec_out);
            }
        }
        ++ep; gbar2(arr, go, ep);
    }

    // =================== projection: [16384,512](f16) @ [512,128] + b ======
    {
        int rowb = bid * 64 + wave * 16;
        f32x4 acc[8];
#pragma unroll
        for (int nt = 0; nt < 8; ++nt) {
            float bv = projb[nt * 16 + c];
            f32x4 tmp = {bv, bv, bv, bv};
            acc[nt] = tmp;
        }
        const u16* ap = dec_out + (size_t)(rowb + c) * HH + kgrp * 8;
#pragma unroll
        for (int kt = 0; kt < 16; ++kt) {
            half8 ah = as_half8(*(const uint4*)(ap + kt * 32));
#pragma unroll
            for (int nt = 0; nt < 8; ++nt) {
                half8 bh = as_half8(*(const uint4*)(prt + ((size_t)(kt * 8 + nt) * 64 + lane) * 8));
                acc[nt] = __builtin_amdgcn_mfma_f32_16x16x32_f16(ah, bh, acc[nt], 0, 0, 0);
            }
        }
#pragma unroll
        for (int nt = 0; nt < 8; ++nt)
#pragma unroll
            for (int r = 0; r < 4; ++r)
                dout[(size_t)(rowb + kgrp * 4 + r) * VV + nt * 16 + c] = acc[nt][r];
    }
}

// ---------------------------------------------------------------------------
extern "C" void kernel_launch(void* const* d_in, const int* in_sizes, int n_in,
                              void* d_out, int out_size, void* d_ws, size_t ws_size,
                              hipStream_t stream)
{
    const int*   en_in  = (const int*)  d_in[0];
    const int*   en_len = (const int*)  d_in[1];
    const int*   de_in  = (const int*)  d_in[2];
    const int*   de_len = (const int*)  d_in[3];
    const float* embed  = (const float*)d_in[4];
    const float* encW0  = (const float*)d_in[5];
    const float* encb0  = (const float*)d_in[6];
    const float* encW1  = (const float*)d_in[7];
    const float* encb1  = (const float*)d_in[8];
    const float* decW0  = (const float*)d_in[9];
    const float* decb0  = (const float*)d_in[10];
    const float* decW1  = (const float*)d_in[11];
    const float* decb1  = (const float*)d_in[12];
    const float* projW  = (const float*)d_in[13];
    const float* projb  = (const float*)d_in[14];

    char* base = (char*)d_ws;
    size_t off = 0;
    auto alloc = [&](size_t bytes) -> void* {
        void* r = base + off;
        off = (off + bytes + 255) & ~(size_t)255;
        return r;
    };

    u16* hbuf    = (u16*)alloc((size_t)8 * BH * sizeof(u16));       // 512 KB
    u16* dec_out = (u16*)alloc((size_t)BB * TT * HH * sizeof(u16)); // 16 MB
    int* arr     = (int*)alloc((size_t)NBLK * 64 * sizeof(int));    // 64 KB, 1 line/block
    int* go      = (int*)alloc(64 * sizeof(int));

    auto aw = [&](size_t elems) -> u16* { return (u16*)alloc(elems * sizeof(u16)); };
    const size_t szK768  = (size_t)128 * 24 * 1024;
    const size_t szK1024 = (size_t)128 * 32 * 1024;
    const size_t szK512  = (size_t)128 * 16 * 1024;
    u16* e0t = aw(szK768);
    u16* e1t = aw(szK1024);
    u16* d0t = aw(szK768);
    u16* d1t = aw(szK1024);
    u16* dmt = aw(szK512);
    u16* prh = aw((size_t)512 * VV);
    u16* prl = aw((size_t)512 * VV);
    u16* embh = aw((size_t)VV * EE);
    u16* embl = aw((size_t)VV * EE);

    auto pack = [&](const float* W, u16* dst, int KT, int thresh, int rowoff) {
        int total = 128 * KT * 1024;
        split_pack<<<(total + 255) / 256, 256, 0, stream>>>(W, dst, KT, thresh, rowoff, total);
    };
    pack(encW0, e0t, 24, 768,  0);    // rows 0..767
    pack(encW1, e1t, 32, 1024, 0);
    pack(decW0, d0t, 24, 256,  512);  // rows {0..255, 768..1279}
    pack(decW0, dmt, 16, 0,    256);  // rows 256..767 (en_last block)
    pack(decW1, d1t, 32, 1024, 0);
    {
        int total = 512 * 8 * 16;
        split_tile<<<(total + 255) / 256, 256, 0, stream>>>(projW, prh, prl, 8, VV, total);
    }
    {
        int total = VV * EE;
        split_embed<<<(total + 255) / 256, 256, 0, stream>>>(embed, embh, embl, total);
    }

    hipMemsetAsync(hbuf, 0, (size_t)8 * BH * sizeof(u16), stream);
    hipMemsetAsync(arr, 0, (size_t)NBLK * 64 * sizeof(int), stream);
    hipMemsetAsync(go, 0, 64 * sizeof(int), stream);

    persist<<<NBLK, 256, 0, stream>>>(
        e0t, e1t, d0t, d1t, dmt, prh, embh, embl,
        en_in, en_len, de_in, de_len,
        encb0, encb1, decb0, decb1, projb,
        hbuf, dec_out, arr, go, (float*)d_out);
}

// Round 5
// 5414.465 us; speedup vs baseline: 4.7631x; 1.5900x over previous
//
#include <hip/hip_runtime.h>

#define BB   64
#define TT   256
#define EE   256
#define HH   512
#define VV   128
#define NBLK 256
#define BH   (BB*HH)   // 32768 per h buffer

typedef unsigned short u16;
typedef _Float16 half8 __attribute__((ext_vector_type(8)));
typedef float    f32x4 __attribute__((ext_vector_type(4)));

static __device__ __forceinline__ half8 as_half8(uint4 v) { return __builtin_bit_cast(half8, v); }
static __device__ __forceinline__ u16  h_bits(_Float16 h) { return __builtin_bit_cast(u16, h); }

// waitcnt + sched barrier (mask 0x384 = SALU|DS: lets LDS reads prefetch across,
// blocks MFMA/VALU from hoisting above the wait — guide rule #18)
#define WAITV(n) do { asm volatile("s_waitcnt vmcnt(" #n ")" ::: "memory"); \
                      __builtin_amdgcn_sched_barrier(0x384); } while (0)

// coherent (MALL-direct) and plain 16B loads; coherent short store
template<bool SC>
static __device__ __forceinline__ void issue_load16(uint4& d, const u16* p) {
    if constexpr (SC)
        asm volatile("global_load_dwordx4 %0, %1, off sc0 sc1" : "=v"(d) : "v"(p));
    else
        asm volatile("global_load_dwordx4 %0, %1, off" : "=v"(d) : "v"(p));
}
static __device__ __forceinline__ void store_short_sc(u16* p, u16 v) {
    unsigned vv = v;
    asm volatile("global_store_short %0, %1, off sc0 sc1" :: "v"(p), "v"(vv) : "memory");
}

// ---------------------------------------------------------------------------
// Weight / embed preprocessing (unchanged from R3/R4)
// ---------------------------------------------------------------------------
__global__ void split_pack(const float* __restrict__ W, u16* __restrict__ dst,
                           int KT, int thresh, int rowoff, int total)
{
    int o = blockIdx.x * 256 + threadIdx.x;
    if (o >= total) return;
    int i    = o & 7;
    int lane = (o >> 3) & 63;
    int hl   = (o >> 9) & 1;
    int rest = o >> 10;
    int kt   = rest % KT;
    int wg   = rest / KT;
    int c  = lane & 15;
    int n  = (c >> 2) * 512 + wg * 4 + (c & 3);
    int k  = kt * 32 + ((lane >> 4) << 3) + i;
    int srcrow = (k < thresh) ? k : (k + rowoff);
    float a = W[(size_t)srcrow * 2048 + n];
    _Float16 ah = (_Float16)a;
    dst[o] = hl ? h_bits((_Float16)((a - (float)ah) * 2048.0f)) : h_bits(ah);
}

__global__ void split_tile(const float* __restrict__ W,
                           u16* __restrict__ dh, u16* __restrict__ dl,
                           int NTt, int nsrc, int total)
{
    int o = blockIdx.x * 256 + threadIdx.x;
    if (o >= total) return;
    int i    = o & 7;
    int lane = (o >> 3) & 63;
    int tile = o >> 9;
    int nt   = tile % NTt;
    int kt   = tile / NTt;
    int k = kt * 32 + ((lane >> 4) << 3) + i;
    int n = nt * 16 + (lane & 15);
    float a = W[(size_t)k * nsrc + n];
    _Float16 ah = (_Float16)a;
    dh[o] = h_bits(ah);
    dl[o] = h_bits((_Float16)((a - (float)ah) * 2048.0f));
}

__global__ void split_embed(const float* __restrict__ E,
                            u16* __restrict__ hi, u16* __restrict__ lo, int total)
{
    int o = blockIdx.x * 256 + threadIdx.x;
    if (o >= total) return;
    float a = E[o];
    _Float16 ah = (_Float16)a;
    hi[o] = h_bits(ah);
    lo[o] = h_bits((_Float16)((a - (float)ah) * 2048.0f));
}

// ---------------------------------------------------------------------------
// K-loop with 4-deep asm load ring. Chunks [0,S1): plain-cached (emb),
// [S1,S2): coherent seg2 (h), [S2,KT): coherent seg3 (h). B from LDS.
// Counted vmcnt(6) steady state; vmcnt(0) once before the 4-chunk tail.
// ---------------------------------------------------------------------------
template<int KT, int S1, int S2>
static __device__ __forceinline__ void dostep2(const uint4* __restrict__ ldsl,
    const u16* __restrict__ b1h, const u16* __restrict__ b1l,
    const u16* __restrict__ b2h, const u16* __restrict__ b2l,
    const u16* __restrict__ b3h, const u16* __restrict__ b3l,
    f32x4& acch, f32x4& accl)
{
    uint4 rh[4], rl[4];
    auto issue = [&](int kt, uint4& dh, uint4& dl) {
        if (kt < S1)      { issue_load16<false>(dh, b1h + kt * 32);
                            issue_load16<false>(dl, b1l + kt * 32); }
        else if (kt < S2) { issue_load16<true >(dh, b2h + (kt - S1) * 32);
                            issue_load16<true >(dl, b2l + (kt - S1) * 32); }
        else              { issue_load16<true >(dh, b3h + (kt - S2) * 32);
                            issue_load16<true >(dl, b3l + (kt - S2) * 32); }
    };
#pragma unroll
    for (int p = 0; p < 4; ++p) issue(p, rh[p], rl[p]);
#pragma unroll
    for (int kt = 0; kt < KT; ++kt) {
        if (kt < KT - 4)       WAITV(6);
        else if (kt == KT - 4) WAITV(0);
        half8 ah = as_half8(rh[kt & 3]);
        half8 al = as_half8(rl[kt & 3]);
        half8 bh = as_half8(ldsl[(kt * 2 + 0) * 64]);
        half8 bl = as_half8(ldsl[(kt * 2 + 1) * 64]);
        acch = __builtin_amdgcn_mfma_f32_16x16x32_f16(ah, bh, acch, 0, 0, 0);
        accl = __builtin_amdgcn_mfma_f32_16x16x32_f16(ah, bl, accl, 0, 0, 0);
        accl = __builtin_amdgcn_mfma_f32_16x16x32_f16(al, bh, accl, 0, 0, 0);
        if (kt + 4 < KT) issue(kt + 4, rh[kt & 3], rl[kt & 3]);
    }
}

// ---------------------------------------------------------------------------
// Mailbox grid barrier: NO acquire/release, NO cache maintenance.
// Safety: (a) producers' sc-stores are drained by __syncthreads' vmcnt(0)
// before the arrival flag store; (b) all cross-step data reads are volatile
// asm sc-loads issued after the poll branch (cannot be hoisted by compiler,
// and read MALL where the data already resides).
// ---------------------------------------------------------------------------
static __device__ __forceinline__ void gbar_fast(int* __restrict__ arr,
                                                 int* __restrict__ leaf, int ep)
{
    __syncthreads();   // per-wave vmcnt(0) drain + block sync
    const int t = threadIdx.x;
    if (blockIdx.x == 0) {
        if (t > 0) {
            int* p = arr + t * 64;
            while (__hip_atomic_load(p, __ATOMIC_RELAXED, __HIP_MEMORY_SCOPE_AGENT) < ep) {}
        }
        __syncthreads();
        if (t < 16)
            __hip_atomic_store(leaf + t * 64, ep, __ATOMIC_RELAXED,
                               __HIP_MEMORY_SCOPE_AGENT);
    } else {
        if (t == 0) {
            __hip_atomic_store(arr + blockIdx.x * 64, ep, __ATOMIC_RELAXED,
                               __HIP_MEMORY_SCOPE_AGENT);
            int* p = leaf + (blockIdx.x & 15) * 64;
            while (__hip_atomic_load(p, __ATOMIC_RELAXED, __HIP_MEMORY_SCOPE_AGENT) < ep) {}
        }
        __syncthreads();
    }
}

// ---------------------------------------------------------------------------
// Persistent kernel (structure identical to R3; transport swapped to mailbox)
// ---------------------------------------------------------------------------
__global__ __launch_bounds__(256) void persist(
    const u16* __restrict__ e0t, const u16* __restrict__ e1t,
    const u16* __restrict__ d0t, const u16* __restrict__ d1t,
    const u16* __restrict__ dmt, const u16* __restrict__ prt,
    const u16* __restrict__ embh, const u16* __restrict__ embl,
    const int* __restrict__ en_in, const int* __restrict__ en_len,
    const int* __restrict__ de_in, const int* __restrict__ de_len,
    const float* __restrict__ encb0, const float* __restrict__ encb1,
    const float* __restrict__ decb0, const float* __restrict__ decb1,
    const float* __restrict__ projb,
    u16* __restrict__ hbuf, u16* __restrict__ dec_out,
    int* __restrict__ arr, int* __restrict__ leaf, float* __restrict__ dout)
{
    __shared__ uint4 lds[4096];   // 64 KB

    const int tid  = threadIdx.x;
    const int lane = tid & 63;
    const int wave = tid >> 6;
    const int bid  = blockIdx.x;
    const int layer = bid >> 7;
    const int g     = bid & 127;
    const int c    = lane & 15;
    const int q    = c >> 2;
    const int hd   = c & 3;
    const int kgrp = lane >> 4;
    const int d    = g * 4 + hd;
    const int arow  = wave * 16 + c;        // A-fragment batch row
    const int bbase = wave * 16 + kgrp * 4; // C rows base
    const float inv2048 = 1.0f / 2048.0f;
    const uint4* ldsl = lds + lane;
    int ep = 0;

    auto HB = [&](int which, int p) -> u16* {  // 0=h0hi 1=h0lo 2=h1hi 3=h1lo
        return hbuf + (size_t)(which * 2 + p) * BH;
    };

    int lenE[4], lenD[4];
#pragma unroll
    for (int r = 0; r < 4; ++r) { lenE[r] = en_len[bbase + r]; lenD[r] = de_len[bbase + r]; }

    float cst[4]  = {0.f, 0.f, 0.f, 0.f};
    float hreg[4] = {0.f, 0.f, 0.f, 0.f};

    const float bE  = (layer ? encb1 : encb0)[q * HH + d];
    const float bD1 = decb1[q * HH + d];

    // epilogue: gather 4 gates across lanes, LSTM cell, masked state update.
    // h published via coherent (sc) short stores; dec_out stays plain-cached.
    auto epi = [&](f32x4 acch, f32x4 accl, const int* lens, int t,
                   u16* whh, u16* whl, u16* dot) {
        float zi[4], zj[4], zf[4], zo[4];
        int lb = lane & 0x33;
#pragma unroll
        for (int r = 0; r < 4; ++r) {
            float z = acch[r] + accl[r] * inv2048;
            zi[r] = __shfl(z, lb,      64);
            zj[r] = __shfl(z, lb | 4,  64);
            zf[r] = __shfl(z, lb | 8,  64);
            zo[r] = __shfl(z, lb | 12, 64);
        }
#pragma unroll
        for (int r = 0; r < 4; ++r) {
            int b = bbase + r;
            float fs = 1.f / (1.f + expf(-(zf[r] + 1.f)));
            float is = 1.f / (1.f + expf(-zi[r]));
            float jt = tanhf(zj[r]);
            float os = 1.f / (1.f + expf(-zo[r]));
            float nc = cst[r] * fs + is * jt;
            float nh = tanhf(nc) * os;
            bool mk = (t < lens[r]);
            nc = mk ? nc : cst[r];
            nh = mk ? nh : hreg[r];
            cst[r] = nc; hreg[r] = nh;
            if (q == 0) {
                _Float16 hh = (_Float16)nh;
                _Float16 hl = (_Float16)((nh - (float)hh) * 2048.0f);
                store_short_sc(whh + b * HH + d, h_bits(hh));
                store_short_sc(whl + b * HH + d, h_bits(hl));
                if (dot) {
                    _Float16 ov = (_Float16)(mk ? nh : 0.0f);
                    dot[((size_t)b * TT + t) * HH + d] = h_bits(ov);
                }
            }
        }
    };

    // ---- stage encoder weights to LDS (read-only, plain cached)
    {
        const u16* src = layer ? e1t : e0t;
        int nv = (layer ? 32 : 24) * 128;
        const uint4* s4 = (const uint4*)src + (size_t)g * nv;
        for (int j = tid; j < nv; j += 256) lds[j] = s4[j];
    }
    __syncthreads();

    // =================== encoder ===================
    for (int k = 0; k <= 256; ++k) {
        if (layer == 0) {
            if (k < 256) {
                int t = k, p = k & 1, pp = p ^ 1;
                int tok = en_in[arow * TT + t];
                const u16* pEh = embh + (size_t)tok * EE + kgrp * 8;
                const u16* pEl = embl + (size_t)tok * EE + kgrp * 8;
                const u16* pHh = HB(0, pp) + (size_t)arow * HH + kgrp * 8;
                const u16* pHl = HB(1, pp) + (size_t)arow * HH + kgrp * 8;
                f32x4 acch = {bE, bE, bE, bE}, accl = {0.f, 0.f, 0.f, 0.f};
                dostep2<24, 8, 24>(ldsl, pEh, pEl, pHh, pHl, pHh, pHl, acch, accl);
                epi(acch, accl, lenE, t, HB(0, p), HB(1, p), nullptr);
            }
        } else {
            if (k >= 1) {
                int t = k - 1, p = t & 1, pp = p ^ 1;
                const u16* p0h = HB(0, p)  + (size_t)arow * HH + kgrp * 8;
                const u16* p0l = HB(1, p)  + (size_t)arow * HH + kgrp * 8;
                const u16* p1h = HB(2, pp) + (size_t)arow * HH + kgrp * 8;
                const u16* p1l = HB(3, pp) + (size_t)arow * HH + kgrp * 8;
                f32x4 acch = {bE, bE, bE, bE}, accl = {0.f, 0.f, 0.f, 0.f};
                dostep2<32, 0, 16>(ldsl, p0h, p0l, p0h, p0l, p1h, p1l, acch, accl);
                epi(acch, accl, lenE, t, HB(2, p), HB(3, p), nullptr);
            }
        }
        ++ep; gbar_fast(arr, leaf, ep);
    }

    // =================== prefix (dec L0 z-init from en_last) + LDS reload ===
    f32x4 prefreg = {0.f, 0.f, 0.f, 0.f};
    if (layer == 0) {
        float bv = decb0[q * HH + d];
        f32x4 ph = {bv, bv, bv, bv}, pl = {0.f, 0.f, 0.f, 0.f};
        const u16* s0h = HB(2, 1) + (size_t)arow * HH + kgrp * 8;
        const u16* s0l = HB(3, 1) + (size_t)arow * HH + kgrp * 8;
#pragma unroll
        for (int kt = 0; kt < 16; ++kt) {
            uint4 vh, vl;
            issue_load16<true>(vh, s0h + kt * 32);
            issue_load16<true>(vl, s0l + kt * 32);
            const u16* bb = dmt + (size_t)(g * 16 + kt) * 1024;
            half8 bh = as_half8(*(const uint4*)(bb + lane * 8));
            half8 bl = as_half8(*(const uint4*)(bb + 512 + lane * 8));
            WAITV(0);
            half8 ah = as_half8(vh);
            half8 al = as_half8(vl);
            ph = __builtin_amdgcn_mfma_f32_16x16x32_f16(ah, bh, ph, 0, 0, 0);
            pl = __builtin_amdgcn_mfma_f32_16x16x32_f16(ah, bl, pl, 0, 0, 0);
            pl = __builtin_amdgcn_mfma_f32_16x16x32_f16(al, bh, pl, 0, 0, 0);
        }
#pragma unroll
        for (int r = 0; r < 4; ++r) prefreg[r] = ph[r] + pl[r] * inv2048;
    }
    __syncthreads();
    {
        const u16* src = layer ? d1t : d0t;
        int nv = (layer ? 32 : 24) * 128;
        const uint4* s4 = (const uint4*)src + (size_t)g * nv;
        for (int j = tid; j < nv; j += 256) lds[j] = s4[j];
    }
    __syncthreads();
    ++ep; gbar_fast(arr, leaf, ep);

    // =================== decoder ===================
    for (int k = 0; k <= 256; ++k) {
        if (layer == 0) {
            if (k < 256) {
                int t = k, p = k & 1, pp = p ^ 1;
                int tok = de_in[arow * TT + t];
                const u16* pEh = embh + (size_t)tok * EE + kgrp * 8;
                const u16* pEl = embl + (size_t)tok * EE + kgrp * 8;
                const u16* pHh = HB(0, pp) + (size_t)arow * HH + kgrp * 8;
                const u16* pHl = HB(1, pp) + (size_t)arow * HH + kgrp * 8;
                f32x4 acch = prefreg, accl = {0.f, 0.f, 0.f, 0.f};
                dostep2<24, 8, 24>(ldsl, pEh, pEl, pHh, pHl, pHh, pHl, acch, accl);
                epi(acch, accl, lenD, t, HB(0, p), HB(1, p), nullptr);
            }
        } else {
            if (k >= 1) {
                int t = k - 1, p = t & 1, pp = p ^ 1;
                const u16* p0h = HB(0, p)  + (size_t)arow * HH + kgrp * 8;
                const u16* p0l = HB(1, p)  + (size_t)arow * HH + kgrp * 8;
                const u16* p1h = HB(2, pp) + (size_t)arow * HH + kgrp * 8;
                const u16* p1l = HB(3, pp) + (size_t)arow * HH + kgrp * 8;
                f32x4 acch = {bD1, bD1, bD1, bD1}, accl = {0.f, 0.f, 0.f, 0.f};
                dostep2<32, 0, 16>(ldsl, p0h, p0l, p0h, p0l, p1h, p1l, acch, accl);
                epi(acch, accl, lenD, t, HB(2, p), HB(3, p), dec_out);
            }
        }
        ++ep; gbar_fast(arr, leaf, ep);
    }

    // one heavyweight flush/invalidate pair for plain-cached dec_out
    __threadfence();
    ++ep; gbar_fast(arr, leaf, ep);
    __threadfence();

    // =================== projection: [16384,512](f16) @ [512,128] + b ======
    {
        int rowb = bid * 64 + wave * 16;
        f32x4 acc[8];
#pragma unroll
        for (int nt = 0; nt < 8; ++nt) {
            float bv = projb[nt * 16 + c];
            f32x4 tmp = {bv, bv, bv, bv};
            acc[nt] = tmp;
        }
        const u16* ap = dec_out + (size_t)(rowb + c) * HH + kgrp * 8;
#pragma unroll
        for (int kt = 0; kt < 16; ++kt) {
            half8 ah = as_half8(*(const uint4*)(ap + kt * 32));
#pragma unroll
            for (int nt = 0; nt < 8; ++nt) {
                half8 bh = as_half8(*(const uint4*)(prt + ((size_t)(kt * 8 + nt) * 64 + lane) * 8));
                acc[nt] = __builtin_amdgcn_mfma_f32_16x16x32_f16(ah, bh, acc[nt], 0, 0, 0);
            }
        }
#pragma unroll
        for (int nt = 0; nt < 8; ++nt)
#pragma unroll
            for (int r = 0; r < 4; ++r)
                dout[(size_t)(rowb + kgrp * 4 + r) * VV + nt * 16 + c] = acc[nt][r];
    }
}

// ---------------------------------------------------------------------------
extern "C" void kernel_launch(void* const* d_in, const int* in_sizes, int n_in,
                              void* d_out, int out_size, void* d_ws, size_t ws_size,
                              hipStream_t stream)
{
    const int*   en_in  = (const int*)  d_in[0];
    const int*   en_len = (const int*)  d_in[1];
    const int*   de_in  = (const int*)  d_in[2];
    const int*   de_len = (const int*)  d_in[3];
    const float* embed  = (const float*)d_in[4];
    const float* encW0  = (const float*)d_in[5];
    const float* encb0  = (const float*)d_in[6];
    const float* encW1  = (const float*)d_in[7];
    const float* encb1  = (const float*)d_in[8];
    const float* decW0  = (const float*)d_in[9];
    const float* decb0  = (const float*)d_in[10];
    const float* decW1  = (const float*)d_in[11];
    const float* decb1  = (const float*)d_in[12];
    const float* projW  = (const float*)d_in[13];
    const float* projb  = (const float*)d_in[14];

    char* base = (char*)d_ws;
    size_t off = 0;
    auto alloc = [&](size_t bytes) -> void* {
        void* r = base + off;
        off = (off + bytes + 255) & ~(size_t)255;
        return r;
    };

    u16* hbuf    = (u16*)alloc((size_t)8 * BH * sizeof(u16));       // 512 KB
    u16* dec_out = (u16*)alloc((size_t)BB * TT * HH * sizeof(u16)); // 16 MB
    int* arr     = (int*)alloc((size_t)NBLK * 64 * sizeof(int));    // 1 line/block
    int* leaf    = (int*)alloc((size_t)16 * 64 * sizeof(int));      // 16 lines

    auto aw = [&](size_t elems) -> u16* { return (u16*)alloc(elems * sizeof(u16)); };
    const size_t szK768  = (size_t)128 * 24 * 1024;
    const size_t szK1024 = (size_t)128 * 32 * 1024;
    const size_t szK512  = (size_t)128 * 16 * 1024;
    u16* e0t = aw(szK768);
    u16* e1t = aw(szK1024);
    u16* d0t = aw(szK768);
    u16* d1t = aw(szK1024);
    u16* dmt = aw(szK512);
    u16* prh = aw((size_t)512 * VV);
    u16* prl = aw((size_t)512 * VV);
    u16* embh = aw((size_t)VV * EE);
    u16* embl = aw((size_t)VV * EE);

    auto pack = [&](const float* W, u16* dst, int KT, int thresh, int rowoff) {
        int total = 128 * KT * 1024;
        split_pack<<<(total + 255) / 256, 256, 0, stream>>>(W, dst, KT, thresh, rowoff, total);
    };
    pack(encW0, e0t, 24, 768,  0);    // rows 0..767
    pack(encW1, e1t, 32, 1024, 0);
    pack(decW0, d0t, 24, 256,  512);  // rows {0..255, 768..1279}
    pack(decW0, dmt, 16, 0,    256);  // rows 256..767 (en_last block)
    pack(decW1, d1t, 32, 1024, 0);
    {
        int total = 512 * 8 * 16;
        split_tile<<<(total + 255) / 256, 256, 0, stream>>>(projW, prh, prl, 8, VV, total);
    }
    {
        int total = VV * EE;
        split_embed<<<(total + 255) / 256, 256, 0, stream>>>(embed, embh, embl, total);
    }

    hipMemsetAsync(hbuf, 0, (size_t)8 * BH * sizeof(u16), stream);
    hipMemsetAsync(arr, 0, (size_t)NBLK * 64 * sizeof(int), stream);
    hipMemsetAsync(leaf, 0, (size_t)16 * 64 * sizeof(int), stream);

    persist<<<NBLK, 256, 0, stream>>>(
        e0t, e1t, d0t, d1t, dmt, prh, embh, embl,
        en_in, en_len, de_in, de_len,
        encb0, encb1, decb0, decb1, projb,
        hbuf, dec_out, arr, leaf, (float*)d_out);
}